// Round 3
// baseline (441.940 us; speedup 1.0000x reference)
//
#include <hip/hip_runtime.h>

#define NN 8192
#define FIN 512
#define FOUT 64
#define LRELU_ALPHA 0.2f
#define LOG2E 1.4426950408889634f
#define NSTRIP 4
#define STRIPC (NN / NSTRIP)          // 2048 cols per block strip
#define WAVEC  (STRIPC / 4)           // 512 cols per wave

typedef __attribute__((ext_vector_type(4))) float f32x4;
typedef __attribute__((ext_vector_type(4))) int i32x4;
typedef __attribute__((ext_vector_type(8))) __bf16 bf16x8;

#if __has_builtin(__builtin_amdgcn_exp2f)
#define EXP2F(x) __builtin_amdgcn_exp2f(x)
#else
#define EXP2F(x) exp2f(x)
#endif

// Kernel A: Wh = x@W (fp32), s1/s2 = Wh@a1/a2, WhbT bf16 transpose (64 x 8192).
// One wave per row; K split 4-way across lane groups. 2048 blocks.
__global__ __launch_bounds__(256) void gat_wh(
    const float* __restrict__ x, const float* __restrict__ W,
    const float* __restrict__ A,
    __bf16* __restrict__ WhbT, float* __restrict__ s1, float* __restrict__ s2)
{
    const int gid  = blockIdx.x * 256 + threadIdx.x;
    const int row  = gid >> 6;            // one wave per row
    const int lane = threadIdx.x & 63;
    const int cg   = lane & 15;           // output col group (4 cols)
    const int kh   = lane >> 4;           // k-quarter 0..3

    f32x4 acc = {0.f, 0.f, 0.f, 0.f};
    const float* xrow = x + (size_t)row * FIN + kh * 128;
    const float* wcol = W + cg * 4 + (size_t)kh * 128 * FOUT;

    #pragma unroll 4
    for (int k = 0; k < 128; k += 4) {
        f32x4 xv = *reinterpret_cast<const f32x4*>(xrow + k);
        #pragma unroll
        for (int u = 0; u < 4; ++u) {
            f32x4 wv = *reinterpret_cast<const f32x4*>(wcol + (size_t)(k + u) * FOUT);
            acc += xv[u] * wv;
        }
    }

    // sum the 4 k-quarters (butterfly over lane bits 4,5)
    #pragma unroll
    for (int u = 0; u < 4; ++u) {
        acc[u] += __shfl_xor(acc[u], 16);
        acc[u] += __shfl_xor(acc[u], 32);
    }

    f32x4 a1v = *reinterpret_cast<const f32x4*>(A + cg * 4);
    f32x4 a2v = *reinterpret_cast<const f32x4*>(A + FOUT + cg * 4);
    float s1p = acc[0]*a1v[0] + acc[1]*a1v[1] + acc[2]*a1v[2] + acc[3]*a1v[3];
    float s2p = acc[0]*a2v[0] + acc[1]*a2v[1] + acc[2]*a2v[2] + acc[3]*a2v[3];
    #pragma unroll
    for (int off = 1; off < 16; off <<= 1) {
        s1p += __shfl_xor(s1p, off);
        s2p += __shfl_xor(s2p, off);
    }
    if (lane == 0) { s1[row] = s1p; s2[row] = s2p; }

    if (kh == 0) {
        #pragma unroll
        for (int u = 0; u < 4; ++u)
            WhbT[(size_t)(cg * 4 + u) * NN + row] = (__bf16)acc[u];
    }
}

// Kernel B: fixed-M masked-softmax attention, COLUMN-SPLIT for occupancy.
// M_i = lrelu(s1_i + max_j s2_j) is identical in every strip, so per-strip
// partials (O, l) merge by plain addition. Block = 16 rows x 2048-col strip,
// 4 waves x 512 cols. Grid = 512 row-blocks x 4 strips = 2048 blocks
// (vs 512 before -> 2-3x resident waves/SIMD to hide the adj HBM stream).
__global__ __launch_bounds__(256) void gat_attn(
    const int* __restrict__ adj, const __bf16* __restrict__ WhbT,
    const float* __restrict__ s1g, const float* __restrict__ s2g,
    float* __restrict__ Opart, float* __restrict__ lpart)
{
    __shared__ float s2l[STRIPC];         // this strip's s2 * log2(e)
    __shared__ float red[4];
    __shared__ float ol[4][16];
    __shared__ float oacc[4][16][FOUT];

    const int tid  = threadIdx.x;
    const int w    = tid >> 6;
    const int lane = tid & 63;
    const int r    = lane & 15;           // MFMA A-row / B-col
    const int q    = lane >> 4;           // k-chunk q*8..q*8+7
    const int rowblk  = blockIdx.x >> 2;
    const int cs      = blockIdx.x & 3;   // column strip
    const int row0    = rowblk * 16;
    const int colbase = cs * STRIPC;

    // global max over ALL of s2 (so M is strip-independent); stage only our strip
    float mx = -3.0e38f;
    for (int i = tid; i < NN / 4; i += 256) {
        f32x4 v = reinterpret_cast<const f32x4*>(s2g)[i];
        v *= LOG2E;
        mx = fmaxf(mx, fmaxf(fmaxf(v[0], v[1]), fmaxf(v[2], v[3])));
        const int li = i - cs * (STRIPC / 4);
        if ((unsigned)li < (unsigned)(STRIPC / 4))
            reinterpret_cast<f32x4*>(s2l)[li] = v;
    }
    #pragma unroll
    for (int off = 1; off < 64; off <<= 1)
        mx = fmaxf(mx, __shfl_xor(mx, off));
    if (lane == 0) red[w] = mx;
    __syncthreads();
    const float s2maxl = fmaxf(fmaxf(red[0], red[1]), fmaxf(red[2], red[3]));

    const float s1l = s1g[row0 + r] * LOG2E;
    const float tM  = s1l + s2maxl;
    const float Ml  = fmaxf(tM, LRELU_ALPHA * tM);   // lrelu in log2 domain

    float l = 0.f;
    f32x4 acc0 = {0,0,0,0}, acc1 = {0,0,0,0}, acc2 = {0,0,0,0}, acc3 = {0,0,0,0};

    const int*    adjp = adj + (size_t)(row0 + r) * NN + colbase + (w * WAVEC) + q * 8;
    const __bf16* wp   = WhbT + colbase + (w * WAVEC) + q * 8;
    const float*  s2b_ = s2l + (w * WAVEC) + q * 8;

    for (int it = 0; it < WAVEC / 64; ++it) {         // 8 iterations x 64 cols
        const int j0 = it << 6;
        #pragma unroll
        for (int c = 0; c < 2; ++c) {
            const int jc = j0 + (c << 5);
            i32x4 av0 = *reinterpret_cast<const i32x4*>(adjp + jc);
            i32x4 av1 = *reinterpret_cast<const i32x4*>(adjp + jc + 4);
            bf16x8 b0 = *reinterpret_cast<const bf16x8*>(wp + (size_t)(0 * 16 + r) * NN + jc);
            bf16x8 b1 = *reinterpret_cast<const bf16x8*>(wp + (size_t)(1 * 16 + r) * NN + jc);
            bf16x8 b2 = *reinterpret_cast<const bf16x8*>(wp + (size_t)(2 * 16 + r) * NN + jc);
            bf16x8 b3 = *reinterpret_cast<const bf16x8*>(wp + (size_t)(3 * 16 + r) * NN + jc);
            f32x4 s2a = *reinterpret_cast<const f32x4*>(s2b_ + jc);
            f32x4 s2c = *reinterpret_cast<const f32x4*>(s2b_ + jc + 4);

            bf16x8 af;
            float ps = 0.f;
            #pragma unroll
            for (int i = 0; i < 4; ++i) {
                float t0 = s1l + s2a[i];
                float g0 = fmaxf(t0, LRELU_ALPHA * t0) - Ml;
                g0 = (av0[i] > 0) ? g0 : -3.0e38f;     // masked -> exp2 -> 0
                float p0 = EXP2F(g0);
                ps += p0;
                af[i] = (__bf16)p0;
                float t1 = s1l + s2c[i];
                float g1 = fmaxf(t1, LRELU_ALPHA * t1) - Ml;
                g1 = (av1[i] > 0) ? g1 : -3.0e38f;
                float p1 = EXP2F(g1);
                ps += p1;
                af[i + 4] = (__bf16)p1;
            }
            l += ps;
            acc0 = __builtin_amdgcn_mfma_f32_16x16x32_bf16(af, b0, acc0, 0, 0, 0);
            acc1 = __builtin_amdgcn_mfma_f32_16x16x32_bf16(af, b1, acc1, 0, 0, 0);
            acc2 = __builtin_amdgcn_mfma_f32_16x16x32_bf16(af, b2, acc2, 0, 0, 0);
            acc3 = __builtin_amdgcn_mfma_f32_16x16x32_bf16(af, b3, acc3, 0, 0, 0);
        }
    }

    // reduce over the 4 k-quads, then intra-block merge (plain sums; same M everywhere)
    l += __shfl_xor(l, 16);
    l += __shfl_xor(l, 32);
    if (lane < 16) ol[w][lane] = l;
    #pragma unroll
    for (int reg = 0; reg < 4; ++reg) {
        oacc[w][q * 4 + reg][0 * 16 + r] = acc0[reg];
        oacc[w][q * 4 + reg][1 * 16 + r] = acc1[reg];
        oacc[w][q * 4 + reg][2 * 16 + r] = acc2[reg];
        oacc[w][q * 4 + reg][3 * 16 + r] = acc3[reg];
    }
    __syncthreads();

    for (int o = tid; o < 16 * FOUT; o += 256) {
        const int rr = o >> 6;
        const int f  = o & 63;
        const float L = ol[0][rr] + ol[1][rr] + ol[2][rr] + ol[3][rr];
        const float O = oacc[0][rr][f] + oacc[1][rr][f] + oacc[2][rr][f] + oacc[3][rr][f];
        Opart[((size_t)cs * NN + row0 + rr) * FOUT + f] = O;
        if (f == 0) lpart[cs * NN + row0 + rr] = L;
    }
}

// Kernel C: merge the 4 column-strip partials: out = (sum O)/(sum l) + bias.
__global__ __launch_bounds__(256) void gat_merge(
    const float* __restrict__ Opart, const float* __restrict__ lpart,
    const float* __restrict__ bias, float* __restrict__ out)
{
    const int idx = blockIdx.x * 256 + threadIdx.x;   // 8192 * 16 threads
    const int row = idx >> 4;
    const int fg  = idx & 15;

    f32x4 O = {0.f, 0.f, 0.f, 0.f};
    float L = 0.f;
    #pragma unroll
    for (int cs = 0; cs < NSTRIP; ++cs) {
        O += *reinterpret_cast<const f32x4*>(Opart + ((size_t)cs * NN + row) * FOUT + fg * 4);
        L += lpart[cs * NN + row];
    }
    const f32x4 bv = *reinterpret_cast<const f32x4*>(bias + fg * 4);
    const float inv = 1.0f / L;
    f32x4 res = O * inv + bv;
    *reinterpret_cast<f32x4*>(out + (size_t)row * FOUT + fg * 4) = res;
}

extern "C" void kernel_launch(void* const* d_in, const int* in_sizes, int n_in,
                              void* d_out, int out_size, void* d_ws, size_t ws_size,
                              hipStream_t stream)
{
    const float* x    = (const float*)d_in[0];
    const int*   adj  = (const int*)d_in[1];
    const float* W    = (const float*)d_in[2];
    const float* bias = (const float*)d_in[3];
    const float* A    = (const float*)d_in[4];
    float* out = (float*)d_out;

    // workspace: WhbT (1 MB) | s1 (32 KB) | s2 (32 KB) | Opart (8 MB) | lpart (128 KB)
    char* ws = (char*)d_ws;
    __bf16* WhbT  = (__bf16*)ws;
    float*  s1    = (float*)(ws + (size_t)FOUT * NN * sizeof(__bf16));
    float*  s2    = s1 + NN;
    float*  Opart = s2 + NN;
    float*  lpart = Opart + (size_t)NSTRIP * NN * FOUT;

    gat_wh<<<dim3(NN / 4), dim3(256), 0, stream>>>(x, W, A, WhbT, s1, s2);
    gat_attn<<<dim3(512 * NSTRIP), dim3(256), 0, stream>>>(adj, WhbT, s1, s2, Opart, lpart);
    gat_merge<<<dim3(NN * 16 / 256), dim3(256), 0, stream>>>(Opart, lpart, bias, out);
}

// Round 4
// 409.243 us; speedup vs baseline: 1.0799x; 1.0799x over previous
//
#include <hip/hip_runtime.h>

#define NN 8192
#define FIN 512
#define FOUT 64
#define LRELU_ALPHA 0.2f
#define LOG2E 1.4426950408889634f

typedef __attribute__((ext_vector_type(4))) float f32x4;
typedef __attribute__((ext_vector_type(4))) int i32x4;
typedef __attribute__((ext_vector_type(8))) __bf16 bf16x8;
typedef __attribute__((ext_vector_type(4))) __bf16 bf16x4;

#if __has_builtin(__builtin_amdgcn_exp2f)
#define EXP2F(x) __builtin_amdgcn_exp2f(x)
#else
#define EXP2F(x) exp2f(x)
#endif

// Kernel A: Wh = x@W (fp32), s1/s2 = Wh@a1/a2, WhbT bf16 transpose (64 x 8192).
// FOUR rows per wave: one W fetch feeds 4 FMAs -> W L2 traffic drops from
// 8192x128KB = 1 GB (the round-2 bottleneck) to 256 MB, and the 4-row ILP
// covers L2 latency at 2 waves/SIMD. x is read exactly once (16 MB).
// lane = cg + 16*kh: cg = output col group (4 cols), kh = k-quarter.
__global__ __launch_bounds__(256) void gat_wh(
    const float* __restrict__ x, const float* __restrict__ W,
    const float* __restrict__ A,
    __bf16* __restrict__ WhbT, float* __restrict__ s1, float* __restrict__ s2)
{
    const int wid  = (blockIdx.x * 256 + threadIdx.x) >> 6;
    const int lane = threadIdx.x & 63;
    const int cg   = lane & 15;
    const int kh   = lane >> 4;
    const int row0 = wid * 4;

    f32x4 acc[4];
    #pragma unroll
    for (int r_ = 0; r_ < 4; ++r_) acc[r_] = (f32x4){0.f, 0.f, 0.f, 0.f};

    const float* xb   = x + (size_t)row0 * FIN + kh * 128;
    const float* wcol = W + cg * 4 + (size_t)kh * 128 * FOUT;

    #pragma unroll 2
    for (int k = 0; k < 128; k += 4) {
        f32x4 wv[4];
        #pragma unroll
        for (int u = 0; u < 4; ++u)
            wv[u] = *reinterpret_cast<const f32x4*>(wcol + (size_t)(k + u) * FOUT);
        #pragma unroll
        for (int r_ = 0; r_ < 4; ++r_) {
            f32x4 xv = *reinterpret_cast<const f32x4*>(xb + (size_t)r_ * FIN + k);
            acc[r_] += xv[0] * wv[0];
            acc[r_] += xv[1] * wv[1];
            acc[r_] += xv[2] * wv[2];
            acc[r_] += xv[3] * wv[3];
        }
    }

    // reduce the 4 k-quarters (butterfly over lane bits 4,5)
    #pragma unroll
    for (int r_ = 0; r_ < 4; ++r_) {
        #pragma unroll
        for (int u = 0; u < 4; ++u) {
            acc[r_][u] += __shfl_xor(acc[r_][u], 16);
            acc[r_][u] += __shfl_xor(acc[r_][u], 32);
        }
    }

    f32x4 a1v = *reinterpret_cast<const f32x4*>(A + cg * 4);
    f32x4 a2v = *reinterpret_cast<const f32x4*>(A + FOUT + cg * 4);
    #pragma unroll
    for (int r_ = 0; r_ < 4; ++r_) {
        float s1p = acc[r_][0]*a1v[0] + acc[r_][1]*a1v[1] + acc[r_][2]*a1v[2] + acc[r_][3]*a1v[3];
        float s2p = acc[r_][0]*a2v[0] + acc[r_][1]*a2v[1] + acc[r_][2]*a2v[2] + acc[r_][3]*a2v[3];
        #pragma unroll
        for (int off = 1; off < 16; off <<= 1) {
            s1p += __shfl_xor(s1p, off);
            s2p += __shfl_xor(s2p, off);
        }
        if (lane == 0) { s1[row0 + r_] = s1p; s2[row0 + r_] = s2p; }
    }

    // transpose-store: pack 4 consecutive rows into one 8B bf16x4 store per col
    if (kh == 0) {
        #pragma unroll
        for (int u = 0; u < 4; ++u) {
            bf16x4 pk;
            pk[0] = (__bf16)acc[0][u];
            pk[1] = (__bf16)acc[1][u];
            pk[2] = (__bf16)acc[2][u];
            pk[3] = (__bf16)acc[3][u];
            *reinterpret_cast<bf16x4*>(WhbT + (size_t)(cg * 4 + u) * NN + row0) = pk;
        }
    }
}

// Kernel B: fixed-M masked-softmax attention (round-2 structure — column split
// measurably didn't help, so attn is at/near its 268 MB adj-stream roofline).
// M_i = lrelu(s1_i + max_j s2_j); per-row constants c1 = s1-M, c2 = 0.2*s1-M
// fold the -M and the lrelu slope: g = max(c1 + s2_j, c2 + 0.2*s2_j).
__global__ __launch_bounds__(256) void gat_attn(
    const int* __restrict__ adj, const __bf16* __restrict__ WhbT,
    const float* __restrict__ s1g, const float* __restrict__ s2g,
    const float* __restrict__ bias, float* __restrict__ out)
{
    __shared__ float s2l[NN];             // s2 * log2(e)
    __shared__ float red[4];
    __shared__ float ol[4][16];
    __shared__ float oacc[4][16][FOUT];

    const int tid  = threadIdx.x;
    const int w    = tid >> 6;
    const int lane = tid & 63;
    const int r    = lane & 15;           // MFMA A-row / B-col
    const int q    = lane >> 4;           // k-chunk q*8..q*8+7
    const int row0 = blockIdx.x * 16;

    // stage s2*log2e into LDS, tracking the global max on the way
    float mx = -3.0e38f;
    for (int i = tid; i < NN / 4; i += 256) {
        f32x4 v = reinterpret_cast<const f32x4*>(s2g)[i];
        v *= LOG2E;
        reinterpret_cast<f32x4*>(s2l)[i] = v;
        mx = fmaxf(mx, fmaxf(fmaxf(v[0], v[1]), fmaxf(v[2], v[3])));
    }
    #pragma unroll
    for (int off = 1; off < 64; off <<= 1)
        mx = fmaxf(mx, __shfl_xor(mx, off));
    if (lane == 0) red[w] = mx;
    __syncthreads();
    const float s2maxl = fmaxf(fmaxf(red[0], red[1]), fmaxf(red[2], red[3]));

    const float s1l = s1g[row0 + r] * LOG2E;
    const float tM  = s1l + s2maxl;
    const float Ml  = fmaxf(tM, LRELU_ALPHA * tM);   // lrelu in log2 domain
    const float c1  = s1l - Ml;                       // unmasked branch const
    const float c2  = LRELU_ALPHA * s1l - Ml;         // leaky branch const

    float l = 0.f;
    f32x4 acc0 = {0,0,0,0}, acc1 = {0,0,0,0}, acc2 = {0,0,0,0}, acc3 = {0,0,0,0};

    const int*    adjp = adj + (size_t)(row0 + r) * NN + q * 8;
    const __bf16* wp   = WhbT + q * 8;
    const float*  s2b_ = s2l + q * 8;

    for (int it = 0; it < 32; ++it) {                 // 64 cols per iteration
        const int j0 = (w << 11) + (it << 6);
        #pragma unroll
        for (int c = 0; c < 2; ++c) {
            const int jc = j0 + (c << 5);
            i32x4 av0 = *reinterpret_cast<const i32x4*>(adjp + jc);
            i32x4 av1 = *reinterpret_cast<const i32x4*>(adjp + jc + 4);
            bf16x8 b0 = *reinterpret_cast<const bf16x8*>(wp + (size_t)(0 * 16 + r) * NN + jc);
            bf16x8 b1 = *reinterpret_cast<const bf16x8*>(wp + (size_t)(1 * 16 + r) * NN + jc);
            bf16x8 b2 = *reinterpret_cast<const bf16x8*>(wp + (size_t)(2 * 16 + r) * NN + jc);
            bf16x8 b3 = *reinterpret_cast<const bf16x8*>(wp + (size_t)(3 * 16 + r) * NN + jc);
            f32x4 s2a = *reinterpret_cast<const f32x4*>(s2b_ + jc);
            f32x4 s2c = *reinterpret_cast<const f32x4*>(s2b_ + jc + 4);

            bf16x8 af;
            float ps = 0.f;
            #pragma unroll
            for (int i = 0; i < 4; ++i) {
                float g0 = fmaxf(c1 + s2a[i], fmaf(LRELU_ALPHA, s2a[i], c2));
                g0 = (av0[i] > 0) ? g0 : -3.0e38f;     // masked -> exp2 -> 0
                float p0 = EXP2F(g0);
                ps += p0;
                af[i] = (__bf16)p0;
                float g1 = fmaxf(c1 + s2c[i], fmaf(LRELU_ALPHA, s2c[i], c2));
                g1 = (av1[i] > 0) ? g1 : -3.0e38f;
                float p1 = EXP2F(g1);
                ps += p1;
                af[i + 4] = (__bf16)p1;
            }
            l += ps;
            acc0 = __builtin_amdgcn_mfma_f32_16x16x32_bf16(af, b0, acc0, 0, 0, 0);
            acc1 = __builtin_amdgcn_mfma_f32_16x16x32_bf16(af, b1, acc1, 0, 0, 0);
            acc2 = __builtin_amdgcn_mfma_f32_16x16x32_bf16(af, b2, acc2, 0, 0, 0);
            acc3 = __builtin_amdgcn_mfma_f32_16x16x32_bf16(af, b3, acc3, 0, 0, 0);
        }
    }

    // denominator: reduce over the 4 k-quads once, at the end
    l += __shfl_xor(l, 16);
    l += __shfl_xor(l, 32);
    if (lane < 16) ol[w][lane] = l;
    #pragma unroll
    for (int reg = 0; reg < 4; ++reg) {
        oacc[w][q * 4 + reg][0 * 16 + r] = acc0[reg];
        oacc[w][q * 4 + reg][1 * 16 + r] = acc1[reg];
        oacc[w][q * 4 + reg][2 * 16 + r] = acc2[reg];
        oacc[w][q * 4 + reg][3 * 16 + r] = acc3[reg];
    }
    __syncthreads();

    // cross-wave merge: same fixed M everywhere -> plain sums
    for (int o = tid; o < 16 * FOUT; o += 256) {
        const int rr = o >> 6;
        const int f  = o & 63;
        const float L = ol[0][rr] + ol[1][rr] + ol[2][rr] + ol[3][rr];
        const float O = oacc[0][rr][f] + oacc[1][rr][f] + oacc[2][rr][f] + oacc[3][rr][f];
        out[(size_t)(row0 + rr) * FOUT + f] = O / L + bias[f];
    }
}

extern "C" void kernel_launch(void* const* d_in, const int* in_sizes, int n_in,
                              void* d_out, int out_size, void* d_ws, size_t ws_size,
                              hipStream_t stream)
{
    const float* x    = (const float*)d_in[0];
    const int*   adj  = (const int*)d_in[1];
    const float* W    = (const float*)d_in[2];
    const float* bias = (const float*)d_in[3];
    const float* A    = (const float*)d_in[4];
    float* out = (float*)d_out;

    // workspace: WhbT (1 MB) | s1 (32 KB) | s2 (32 KB)
    char* ws = (char*)d_ws;
    __bf16* WhbT = (__bf16*)ws;
    float*  s1   = (float*)(ws + (size_t)FOUT * NN * sizeof(__bf16));
    float*  s2   = s1 + NN;

    // 2048 waves (4 rows each) in 512 blocks
    gat_wh<<<dim3(512), dim3(256), 0, stream>>>(x, W, A, WhbT, s1, s2);
    gat_attn<<<dim3(NN / 16), dim3(256), 0, stream>>>(adj, WhbT, s1, s2, bias, out);
}